// Round 1
// baseline (858.689 us; speedup 1.0000x reference)
//
#include <hip/hip_runtime.h>
#include <hip/hip_bf16.h>
#include <math.h>

// Sizes
#define BATCH 8192
#define NS 26
#define DDENSE 13
#define DIM 32
#define NF 8

typedef unsigned short bf16_t;

__device__ __forceinline__ float bf2f(bf16_t u) {
    union { unsigned int i; float f; } v; v.i = ((unsigned int)u) << 16; return v.f;
}
__device__ __forceinline__ bf16_t f2bf(float f) {
    union { float f; unsigned int i; } v; v.f = f;
    unsigned int x = v.i;
    unsigned int r = (x + 0x7FFFu + ((x >> 16) & 1u)) >> 16;   // round-to-nearest-even
    return (bf16_t)r;
}

// ---------------------------------------------------------------------------
// K1: embeddings (gather + dense proj) -> conv0(7x1,1->8) + tanh + maxpool2
//     writes pooled0 (B,13,32,8) bf16 and embs_cls (B,27,32) f32
// ---------------------------------------------------------------------------
__global__ __launch_bounds__(256) void k_embed_conv0(
    const int* __restrict__ sp, const float* __restrict__ dn,
    const float* __restrict__ gen_table, const float* __restrict__ gen_W, const float* __restrict__ gen_b,
    const float* __restrict__ cls_table, const float* __restrict__ cls_W, const float* __restrict__ cls_b,
    const float* __restrict__ k0, const float* __restrict__ b0,
    bf16_t* __restrict__ pooled0, float* __restrict__ embs_cls)
{
    __shared__ float embG[27 * 32];
    __shared__ float dloc[13];
    __shared__ int   ids[26];
    __shared__ float k0s[56];
    __shared__ float b0s[8];
    const int b = blockIdx.x;
    const int t = threadIdx.x;

    if (t < 26) ids[t] = sp[b * 26 + t];
    if (t >= 32 && t < 45)  dloc[t - 32] = dn[b * 13 + (t - 32)];
    if (t >= 64 && t < 120) k0s[t - 64] = k0[t - 64];
    if (t >= 120 && t < 128) b0s[t - 120] = b0[t - 120];
    __syncthreads();

    // gather both tables (26 rows x 32)
    for (int i = t; i < 832; i += 256) {
        int s = i >> 5, d = i & 31;
        int id = ids[s];
        embG[i] = gen_table[id * 32 + d];
        embs_cls[(size_t)b * 864 + i] = cls_table[id * 32 + d];
    }
    // dense projections -> row 26
    if (t < 32) {
        float a = gen_b[t];
        #pragma unroll
        for (int k = 0; k < 13; k++) a += dloc[k] * gen_W[k * 32 + t];
        embG[832 + t] = a;
    } else if (t < 64) {
        int c = t - 32;
        float a = cls_b[c];
        #pragma unroll
        for (int k = 0; k < 13; k++) a += dloc[k] * cls_W[k * 32 + c];
        embs_cls[(size_t)b * 864 + 832 + c] = a;
    }
    __syncthreads();

    // conv0 + tanh + maxpool2 over H (27 -> 13)
    const int w = t >> 3, f = t & 7;
    for (int hp = 0; hp < 13; hp++) {
        float m = -1e30f;
        #pragma unroll
        for (int rr = 0; rr < 2; rr++) {
            int r = 2 * hp + rr;
            float acc = b0s[f];
            #pragma unroll
            for (int tap = 0; tap < 7; tap++) {
                int h = r + tap - 3;
                if (h >= 0 && h < 27) acc += embG[h * 32 + w] * k0s[tap * 8 + f];
            }
            m = fmaxf(m, tanhf(acc));
        }
        pooled0[(size_t)b * 3328 + hp * 256 + t] = f2bf(m);
    }
}

// ---------------------------------------------------------------------------
// K2/K4: C = tanh(A @ W + bias), A bf16 (M x K), W f32 (K x 96), C f32 (M x 96)
// 64x96 tile per block, 256 threads, 4x6 microtile
// ---------------------------------------------------------------------------
template<int K>
__global__ __launch_bounds__(256) void k_fc(
    const bf16_t* __restrict__ A, const float* __restrict__ W,
    const float* __restrict__ bias, float* __restrict__ C)
{
    __shared__ float As[64 * 33];   // padded stride 33
    __shared__ float Ws[32 * 96];
    const int t = threadIdx.x;
    const int row0 = blockIdx.x * 64;
    const int tx = t & 15, ty = t >> 4;

    float acc[4][6];
    #pragma unroll
    for (int i = 0; i < 4; i++)
        #pragma unroll
        for (int j = 0; j < 6; j++) acc[i][j] = 0.f;

    for (int k0 = 0; k0 < K; k0 += 32) {
        // stage A tile: each thread one uint4 = 8 bf16
        {
            int r = t >> 2, cg = t & 3;
            const uint4* p = (const uint4*)(A + (size_t)(row0 + r) * K + k0 + cg * 8);
            uint4 v = *p;
            unsigned int vs[4] = { v.x, v.y, v.z, v.w };
            #pragma unroll
            for (int q = 0; q < 4; q++) {
                union { unsigned int i; float f; } lo, hi;
                lo.i = (vs[q] & 0xFFFFu) << 16;
                hi.i = vs[q] & 0xFFFF0000u;
                As[r * 33 + cg * 8 + 2 * q]     = lo.f;
                As[r * 33 + cg * 8 + 2 * q + 1] = hi.f;
            }
        }
        // stage W tile: 32x96 floats = 768 float4
        #pragma unroll
        for (int i = 0; i < 3; i++) {
            int idx = t + 256 * i;
            int r = idx / 24, c4 = idx % 24;
            float4 v = *(const float4*)(W + (size_t)(k0 + r) * 96 + c4 * 4);
            *(float4*)&Ws[r * 96 + c4 * 4] = v;
        }
        __syncthreads();
        #pragma unroll
        for (int k = 0; k < 32; k++) {
            float a[4], w[6];
            #pragma unroll
            for (int i = 0; i < 4; i++) a[i] = As[(ty * 4 + i) * 33 + k];
            #pragma unroll
            for (int j = 0; j < 6; j++) w[j] = Ws[k * 96 + tx * 6 + j];
            #pragma unroll
            for (int i = 0; i < 4; i++)
                #pragma unroll
                for (int j = 0; j < 6; j++) acc[i][j] += a[i] * w[j];
        }
        __syncthreads();
    }
    #pragma unroll
    for (int i = 0; i < 4; i++) {
        int r = row0 + ty * 4 + i;
        #pragma unroll
        for (int j = 0; j < 6; j++) {
            int c = tx * 6 + j;
            C[(size_t)r * 96 + c] = tanhf(acc[i][j] + bias[c]);
        }
    }
}

// ---------------------------------------------------------------------------
// K3: conv1 (7x1, 8->8) + tanh + maxpool2 (13 -> 6). In/out bf16.
// ---------------------------------------------------------------------------
__global__ __launch_bounds__(256) void k_conv1(
    const bf16_t* __restrict__ pooled0, const float* __restrict__ k1,
    const float* __restrict__ b1, bf16_t* __restrict__ pooled1)
{
    __shared__ float x0[8 * 417];   // [fi][h*32+w], padded stride 417
    __shared__ float k1s[448];      // [tap][fi][fo]
    __shared__ float b1s[8];
    const int b = blockIdx.x, t = threadIdx.x;

    for (int i = t; i < 3328; i += 256) {
        int fi = i & 7, p = i >> 3;
        x0[fi * 417 + p] = bf2f(pooled0[(size_t)b * 3328 + i]);
    }
    for (int i = t; i < 448; i += 256) k1s[i] = k1[i];
    if (t < 8) b1s[t] = b1[t];
    __syncthreads();

    const int w = t >> 3, fo = t & 7;
    for (int hp = 0; hp < 6; hp++) {
        float m = -1e30f;
        #pragma unroll
        for (int rr = 0; rr < 2; rr++) {
            int r = 2 * hp + rr;
            float acc = b1s[fo];
            #pragma unroll
            for (int tap = 0; tap < 7; tap++) {
                int h = r + tap - 3;
                if (h >= 0 && h < 13) {
                    #pragma unroll
                    for (int fi = 0; fi < 8; fi++)
                        acc += x0[fi * 417 + h * 32 + w] * k1s[tap * 64 + fi * 8 + fo];
                }
            }
            m = fmaxf(m, tanhf(acc));
        }
        pooled1[(size_t)b * 1536 + hp * 256 + t] = f2bf(m);
    }
}

// ---------------------------------------------------------------------------
// K5: build h = [gram_triu(528), aug_flat(1056)] per sample
// aug = [embs_cls (27x32), feat0 (3x32), feat1 (3x32)]
// ---------------------------------------------------------------------------
__global__ __launch_bounds__(256) void k_build_h(
    const float* __restrict__ embs_cls, const float* __restrict__ feat0,
    const float* __restrict__ feat1, float* __restrict__ h)
{
    __shared__ float aug[1056];
    const int b = blockIdx.x, t = threadIdx.x;
    for (int i = t; i < 864; i += 256) aug[i] = embs_cls[(size_t)b * 864 + i];
    if (t < 96) aug[864 + t] = feat0[(size_t)b * 96 + t];
    else if (t < 192) aug[960 + (t - 96)] = feat1[(size_t)b * 96 + (t - 96)];
    __syncthreads();

    float* hb = h + (size_t)b * 1584;
    for (int i = t; i < 1056; i += 256) hb[528 + i] = aug[i];
    for (int p = t; p < 528; p += 256) {
        int i = 0, rem = p, cnt = 32;
        while (rem >= cnt) { rem -= cnt; cnt--; i++; }
        int j = i + 1 + rem;
        float s = 0.f;
        #pragma unroll
        for (int d = 0; d < 32; d++) s += aug[i * 32 + d] * aug[j * 32 + d];
        hb[p] = s;
    }
}

// ---------------------------------------------------------------------------
// K6: h (8192x1584) @ W1 (1584x128) -> relu -> BN -> dot(outW) -> sigmoid
// 64x128 tile per block, 4x8 microtile
// ---------------------------------------------------------------------------
__global__ __launch_bounds__(256) void k_mlp(
    const float* __restrict__ h, const float* __restrict__ W1,
    const float* __restrict__ b1, const float* __restrict__ gamma,
    const float* __restrict__ beta, const float* __restrict__ mean,
    const float* __restrict__ var, const float* __restrict__ outW,
    const float* __restrict__ outb, float* __restrict__ out)
{
    __shared__ float As[64 * 17];    // padded stride 17
    __shared__ float Ws[16 * 128];
    __shared__ float ht[64 * 129];   // padded stride 129
    __shared__ float bnp[256];
    __shared__ float ow[128];
    const int t = threadIdx.x;
    const int row0 = blockIdx.x * 64;

    if (t < 128) {
        float sc = gamma[t] * rsqrtf(var[t] + 1e-3f);
        bnp[t] = sc;
        bnp[128 + t] = beta[t] - mean[t] * sc;
        ow[t] = outW[t];
    }

    const int tx = t & 15, ty = t >> 4;
    float acc[4][8];
    #pragma unroll
    for (int i = 0; i < 4; i++)
        #pragma unroll
        for (int j = 0; j < 8; j++) acc[i][j] = 0.f;

    for (int k0 = 0; k0 < 1584; k0 += 16) {
        {
            int r = t >> 2, c4 = t & 3;
            float4 v = *(const float4*)(h + (size_t)(row0 + r) * 1584 + k0 + c4 * 4);
            As[r * 17 + c4 * 4 + 0] = v.x;
            As[r * 17 + c4 * 4 + 1] = v.y;
            As[r * 17 + c4 * 4 + 2] = v.z;
            As[r * 17 + c4 * 4 + 3] = v.w;
        }
        #pragma unroll
        for (int i = 0; i < 2; i++) {
            int idx = t + 256 * i;
            int r = idx >> 5, c4 = idx & 31;
            float4 v = *(const float4*)(W1 + (size_t)(k0 + r) * 128 + c4 * 4);
            *(float4*)&Ws[r * 128 + c4 * 4] = v;
        }
        __syncthreads();
        #pragma unroll
        for (int k = 0; k < 16; k++) {
            float a[4];
            #pragma unroll
            for (int i = 0; i < 4; i++) a[i] = As[(ty * 4 + i) * 17 + k];
            float4 w0 = *(const float4*)&Ws[k * 128 + tx * 8];
            float4 w1 = *(const float4*)&Ws[k * 128 + tx * 8 + 4];
            float wv[8] = { w0.x, w0.y, w0.z, w0.w, w1.x, w1.y, w1.z, w1.w };
            #pragma unroll
            for (int i = 0; i < 4; i++)
                #pragma unroll
                for (int j = 0; j < 8; j++) acc[i][j] += a[i] * wv[j];
        }
        __syncthreads();
    }

    #pragma unroll
    for (int i = 0; i < 4; i++) {
        int r = ty * 4 + i;
        #pragma unroll
        for (int j = 0; j < 8; j++) {
            int c = tx * 8 + j;
            float v = acc[i][j] + b1[c];
            v = fmaxf(v, 0.f);
            v = v * bnp[c] + bnp[128 + c];
            ht[r * 129 + c] = v;
        }
    }
    __syncthreads();
    if (t < 64) {
        float s = outb[0];
        #pragma unroll
        for (int c = 0; c < 128; c++) s += ht[t * 129 + c] * ow[c];
        out[row0 + t] = 1.f / (1.f + expf(-s));
    }
}

// ---------------------------------------------------------------------------
extern "C" void kernel_launch(void* const* d_in, const int* in_sizes, int n_in,
                              void* d_out, int out_size, void* d_ws, size_t ws_size,
                              hipStream_t stream) {
    const int*   sp       = (const int*)d_in[0];
    const float* dn       = (const float*)d_in[1];
    const float* gen_tab  = (const float*)d_in[2];
    const float* gen_W    = (const float*)d_in[3];
    const float* gen_b    = (const float*)d_in[4];
    const float* cls_tab  = (const float*)d_in[5];
    const float* cls_W    = (const float*)d_in[6];
    const float* cls_b    = (const float*)d_in[7];
    const float* conv_k0  = (const float*)d_in[8];
    const float* conv_b0  = (const float*)d_in[9];
    const float* fc_W0    = (const float*)d_in[10];
    const float* fc_b0    = (const float*)d_in[11];
    const float* conv_k1  = (const float*)d_in[12];
    const float* conv_b1  = (const float*)d_in[13];
    const float* fc_W1    = (const float*)d_in[14];
    const float* fc_b1    = (const float*)d_in[15];
    const float* mlp_W1   = (const float*)d_in[16];
    const float* mlp_b1   = (const float*)d_in[17];
    const float* bn_gamma = (const float*)d_in[18];
    const float* bn_beta  = (const float*)d_in[19];
    const float* bn_mean  = (const float*)d_in[20];
    const float* bn_var   = (const float*)d_in[21];
    const float* out_W    = (const float*)d_in[22];
    const float* out_b    = (const float*)d_in[23];
    float* out = (float*)d_out;

    // workspace layout (bytes):
    // [0)            pooled0 bf16 B*3328*2 = 54,525,952   (later aliased by h f32 B*1584*4 = 51,904,512)
    // [54,525,952)   pooled1 bf16 B*1536*2 = 25,165,824
    // [79,691,776)   embs_cls f32 B*864*4 = 28,311,552
    // [108,003,328)  feat0 f32 B*96*4 = 3,145,728
    // [111,149,056)  feat1 f32 B*96*4 = 3,145,728
    // total 114,294,784
    char* ws = (char*)d_ws;
    bf16_t* pooled0  = (bf16_t*)(ws + 0);
    bf16_t* pooled1  = (bf16_t*)(ws + 54525952ULL);
    float*  embs_cls = (float*)(ws + 79691776ULL);
    float*  feat0    = (float*)(ws + 108003328ULL);
    float*  feat1    = (float*)(ws + 111149056ULL);
    float*  h        = (float*)(ws + 0);   // aliases pooled0 (safe: consumed by then)

    k_embed_conv0<<<BATCH, 256, 0, stream>>>(sp, dn, gen_tab, gen_W, gen_b,
                                             cls_tab, cls_W, cls_b,
                                             conv_k0, conv_b0, pooled0, embs_cls);
    k_fc<3328><<<BATCH / 64, 256, 0, stream>>>(pooled0, fc_W0, fc_b0, feat0);
    k_conv1<<<BATCH, 256, 0, stream>>>(pooled0, conv_k1, conv_b1, pooled1);
    k_fc<1536><<<BATCH / 64, 256, 0, stream>>>(pooled1, fc_W1, fc_b1, feat1);
    k_build_h<<<BATCH, 256, 0, stream>>>(embs_cls, feat0, feat1, h);
    k_mlp<<<BATCH / 64, 256, 0, stream>>>(h, mlp_W1, mlp_b1, bn_gamma, bn_beta,
                                          bn_mean, bn_var, out_W, out_b, out);
}

// Round 2
// 357.464 us; speedup vs baseline: 2.4022x; 2.4022x over previous
//
#include <hip/hip_runtime.h>
#include <hip/hip_bf16.h>
#include <math.h>

#define BATCH 8192

typedef unsigned short bf16_t;
typedef __attribute__((ext_vector_type(8))) short short8;
typedef __attribute__((ext_vector_type(4))) float f32x4;

__device__ __forceinline__ float bf2f(bf16_t u) {
    union { unsigned int i; float f; } v; v.i = ((unsigned int)u) << 16; return v.f;
}
__device__ __forceinline__ bf16_t f2bf(float f) {
    union { float f; unsigned int i; } v; v.f = f;
    unsigned int x = v.i;
    unsigned int r = (x + 0x7FFFu + ((x >> 16) & 1u)) >> 16;   // RNE
    return (bf16_t)r;
}

// ---------------------------------------------------------------------------
// K0: weight prep — transpose to [N][K] bf16 (Wt2 K-padded 1584->1600 w/ zeros)
// ---------------------------------------------------------------------------
__global__ __launch_bounds__(256) void k_wprep(
    const float* __restrict__ W0, const float* __restrict__ W1,
    const float* __restrict__ W2,
    bf16_t* __restrict__ Wt0, bf16_t* __restrict__ Wt1, bf16_t* __restrict__ Wt2)
{
    int idx = blockIdx.x * 256 + threadIdx.x;
    if (idx < 96 * 3328) { int n = idx / 3328, k = idx - n * 3328; Wt0[idx] = f2bf(W0[(size_t)k * 96 + n]); }
    if (idx < 96 * 1536) { int n = idx / 1536, k = idx - n * 1536; Wt1[idx] = f2bf(W1[(size_t)k * 96 + n]); }
    if (idx < 128 * 1600) {
        int n = idx / 1600, k = idx - n * 1600;
        Wt2[idx] = (k < 1584) ? f2bf(W2[(size_t)k * 128 + n]) : (bf16_t)0;
    }
}

// ---------------------------------------------------------------------------
// K1: embeddings (gather + dense proj) -> conv0(7x1,1->8) + tanh + maxpool2
//     writes pooled0 (B,13,32,8) bf16 and embs_cls (B,27,32) bf16
// ---------------------------------------------------------------------------
__global__ __launch_bounds__(256) void k_embed_conv0(
    const int* __restrict__ sp, const float* __restrict__ dn,
    const float* __restrict__ gen_table, const float* __restrict__ gen_W, const float* __restrict__ gen_b,
    const float* __restrict__ cls_table, const float* __restrict__ cls_W, const float* __restrict__ cls_b,
    const float* __restrict__ k0, const float* __restrict__ b0,
    bf16_t* __restrict__ pooled0, bf16_t* __restrict__ embs_cls)
{
    __shared__ float embG[27 * 32];
    __shared__ float dloc[13];
    __shared__ int   ids[26];
    __shared__ float k0s[56];
    __shared__ float b0s[8];
    const int b = blockIdx.x;
    const int t = threadIdx.x;

    if (t < 26) ids[t] = sp[b * 26 + t];
    if (t >= 32 && t < 45)  dloc[t - 32] = dn[b * 13 + (t - 32)];
    if (t >= 64 && t < 120) k0s[t - 64] = k0[t - 64];
    if (t >= 120 && t < 128) b0s[t - 120] = b0[t - 120];
    __syncthreads();

    for (int i = t; i < 832; i += 256) {
        int s = i >> 5, d = i & 31;
        int id = ids[s];
        embG[i] = gen_table[(size_t)id * 32 + d];
        embs_cls[(size_t)b * 864 + i] = f2bf(cls_table[(size_t)id * 32 + d]);
    }
    if (t < 32) {
        float a = gen_b[t];
        #pragma unroll
        for (int k = 0; k < 13; k++) a += dloc[k] * gen_W[k * 32 + t];
        embG[832 + t] = a;
    } else if (t < 64) {
        int c = t - 32;
        float a = cls_b[c];
        #pragma unroll
        for (int k = 0; k < 13; k++) a += dloc[k] * cls_W[k * 32 + c];
        embs_cls[(size_t)b * 864 + 832 + c] = f2bf(a);
    }
    __syncthreads();

    // conv0 + tanh + pool; thread computes 2 adjacent f -> one 4B store
    const int half = t >> 7;          // hp range split
    const int tt = t & 127;
    const int w = tt >> 2, f0 = (tt & 3) * 2;
    const int hp_beg = half ? 7 : 0, hp_end = half ? 13 : 7;
    for (int hp = hp_beg; hp < hp_end; hp++) {
        float m0 = -1e30f, m1 = -1e30f;
        #pragma unroll
        for (int rr = 0; rr < 2; rr++) {
            int r = 2 * hp + rr;
            float a0 = b0s[f0], a1 = b0s[f0 + 1];
            #pragma unroll
            for (int tap = 0; tap < 7; tap++) {
                int h = r + tap - 3;
                if (h >= 0 && h < 27) {
                    float e = embG[h * 32 + w];
                    a0 += e * k0s[tap * 8 + f0];
                    a1 += e * k0s[tap * 8 + f0 + 1];
                }
            }
            m0 = fmaxf(m0, tanhf(a0));
            m1 = fmaxf(m1, tanhf(a1));
        }
        unsigned int pk = (unsigned int)f2bf(m0) | ((unsigned int)f2bf(m1) << 16);
        *(unsigned int*)(pooled0 + (size_t)b * 3328 + hp * 256 + w * 8 + f0) = pk;
    }
}

// ---------------------------------------------------------------------------
// K2/K4: MFMA GEMM  C_raw = A(bf16, MxK) @ Wt^T(bf16, NxK), N=96
// grid (M/64, 2 split-K). 4 waves/block, wave = 16 rows x 96 cols.
// Fragments loaded directly from global (no LDS). Raw f32 partials out.
// ---------------------------------------------------------------------------
template<int K, int ITERS>
__global__ __launch_bounds__(256) void k_fc_mfma(
    const bf16_t* __restrict__ A, const bf16_t* __restrict__ Wt,
    float* __restrict__ P0, float* __restrict__ P1)
{
    const int t = threadIdx.x;
    const int w = t >> 6, l = t & 63;
    const int lane15 = l & 15, quad = l >> 4;
    const int rowA = blockIdx.x * 64 + w * 16 + lane15;
    const int kb = blockIdx.y * (K / 2);

    const short8* ap = (const short8*)(A + (size_t)rowA * K + kb + quad * 8);
    f32x4 acc[6] = {};

    #pragma unroll 2
    for (int it = 0; it < ITERS; it++) {
        short8 a = ap[it * 4];
        #pragma unroll
        for (int nt = 0; nt < 6; nt++) {
            const short8* bp = (const short8*)(Wt + (size_t)(nt * 16 + lane15) * K + kb + it * 32 + quad * 8);
            acc[nt] = __builtin_amdgcn_mfma_f32_16x16x32_bf16(a, *bp, acc[nt], 0, 0, 0);
        }
    }

    float* P = blockIdx.y ? P1 : P0;
    const int baser = blockIdx.x * 64 + w * 16 + quad * 4;
    #pragma unroll
    for (int nt = 0; nt < 6; nt++)
        #pragma unroll
        for (int i = 0; i < 4; i++)
            P[(size_t)(baser + i) * 96 + nt * 16 + lane15] = acc[nt][i];
}

// ---------------------------------------------------------------------------
// K3: conv1 (7x1, 8->8) + tanh + maxpool2 (13 -> 6), register-cached inputs
// ---------------------------------------------------------------------------
__global__ __launch_bounds__(256) void k_conv1(
    const bf16_t* __restrict__ pooled0, const float* __restrict__ k1,
    const float* __restrict__ b1, bf16_t* __restrict__ pooled1)
{
    __shared__ float x0[8 * 417];   // [fi][h*32+w]
    __shared__ float k1s[448];      // [tap][fi][fo]
    __shared__ float b1s[8];
    const int b = blockIdx.x, t = threadIdx.x;

    for (int i = t; i < 416; i += 256) {
        uint4 v = *(const uint4*)(pooled0 + (size_t)b * 3328 + i * 8);
        unsigned int vs[4] = { v.x, v.y, v.z, v.w };
        #pragma unroll
        for (int q = 0; q < 4; q++) {
            x0[(2 * q) * 417 + i]     = bf2f((bf16_t)(vs[q] & 0xFFFFu));
            x0[(2 * q + 1) * 417 + i] = bf2f((bf16_t)(vs[q] >> 16));
        }
    }
    for (int i = t; i < 448; i += 256) k1s[i] = k1[i];
    if (t < 8) b1s[t] = b1[t];
    __syncthreads();

    const int w = t >> 3, fo = t & 7;
    float acc[12];
    #pragma unroll
    for (int r = 0; r < 12; r++) acc[r] = b1s[fo];

    for (int fi = 0; fi < 8; fi++) {
        float xr[13];
        #pragma unroll
        for (int h = 0; h < 13; h++) xr[h] = x0[fi * 417 + h * 32 + w];
        float kr[7];
        #pragma unroll
        for (int tap = 0; tap < 7; tap++) kr[tap] = k1s[tap * 64 + fi * 8 + fo];
        #pragma unroll
        for (int r = 0; r < 12; r++) {
            #pragma unroll
            for (int tap = 0; tap < 7; tap++) {
                int h = r + tap - 3;
                if (h >= 0 && h < 13) acc[r] += xr[h] * kr[tap];
            }
        }
    }
    #pragma unroll
    for (int hp = 0; hp < 6; hp++) {
        float m = fmaxf(tanhf(acc[2 * hp]), tanhf(acc[2 * hp + 1]));
        pooled1[(size_t)b * 1536 + hp * 256 + t] = f2bf(m);
    }
}

// ---------------------------------------------------------------------------
// K5: fc epilogues (sum split-K partials + bias + tanh) + gram triu + h (bf16)
// h row stride 1600, [528 ip | 1056 aug | 16 zero pad]
// ---------------------------------------------------------------------------
__global__ __launch_bounds__(256) void k_build_h(
    const bf16_t* __restrict__ embs_cls,
    const float* __restrict__ p0a, const float* __restrict__ p0b, const float* __restrict__ fb0,
    const float* __restrict__ p1a, const float* __restrict__ p1b, const float* __restrict__ fb1,
    bf16_t* __restrict__ h)
{
    __shared__ float aug[1056];
    const int b = blockIdx.x, t = threadIdx.x;
    for (int i = t; i < 864; i += 256) aug[i] = bf2f(embs_cls[(size_t)b * 864 + i]);
    if (t < 96) aug[864 + t] = tanhf(p0a[(size_t)b * 96 + t] + p0b[(size_t)b * 96 + t] + fb0[t]);
    else if (t < 192) {
        int j = t - 96;
        aug[960 + j] = tanhf(p1a[(size_t)b * 96 + j] + p1b[(size_t)b * 96 + j] + fb1[j]);
    }
    __syncthreads();

    bf16_t* hb = h + (size_t)b * 1600;
    for (int i = t; i < 1056; i += 256) hb[528 + i] = f2bf(aug[i]);
    if (t < 16) hb[1584 + t] = 0;
    for (int p = t; p < 528; p += 256) {
        int i = 0, rem = p, cnt = 32;
        while (rem >= cnt) { rem -= cnt; cnt--; i++; }
        int j = i + 1 + rem;
        float s = 0.f;
        #pragma unroll
        for (int d = 0; d < 32; d++) s += aug[i * 32 + d] * aug[j * 32 + d];
        hb[p] = f2bf(s);
    }
}

// ---------------------------------------------------------------------------
// K6: MFMA  h(8192x1600 bf16) @ Wt2^T(128x1600 bf16) -> relu -> BN -> outW dot
//     -> sigmoid, fully fused. Block = 32 rows, 4 waves (2 m-tiles x 2 n-halves)
// ---------------------------------------------------------------------------
__global__ __launch_bounds__(256) void k_mlp_mfma(
    const bf16_t* __restrict__ h, const bf16_t* __restrict__ Wt2,
    const float* __restrict__ b1, const float* __restrict__ gamma,
    const float* __restrict__ beta, const float* __restrict__ mean,
    const float* __restrict__ var, const float* __restrict__ outW,
    const float* __restrict__ outb, float* __restrict__ out)
{
    __shared__ float red[64];    // [32 rows][2 n-halves]
    const int t = threadIdx.x, w = t >> 6, l = t & 63;
    const int lane15 = l & 15, quad = l >> 4;
    const int mtile = w >> 1, nhalf = w & 1;
    const int rowA = blockIdx.x * 32 + mtile * 16 + lane15;

    const short8* ap = (const short8*)(h + (size_t)rowA * 1600 + quad * 8);
    f32x4 acc[4] = {};

    #pragma unroll 2
    for (int it = 0; it < 50; it++) {
        short8 a = ap[it * 4];
        #pragma unroll
        for (int nt = 0; nt < 4; nt++) {
            int n = nhalf * 64 + nt * 16 + lane15;
            const short8* bp = (const short8*)(Wt2 + (size_t)n * 1600 + it * 32 + quad * 8);
            acc[nt] = __builtin_amdgcn_mfma_f32_16x16x32_bf16(a, *bp, acc[nt], 0, 0, 0);
        }
    }

    float pl[4] = { 0.f, 0.f, 0.f, 0.f };
    #pragma unroll
    for (int nt = 0; nt < 4; nt++) {
        int c = nhalf * 64 + nt * 16 + lane15;
        float sc = gamma[c] * rsqrtf(var[c] + 1e-3f);
        float sh = beta[c] - mean[c] * sc;
        float ow = outW[c], bb = b1[c];
        #pragma unroll
        for (int i = 0; i < 4; i++) {
            float v = fmaxf(acc[nt][i] + bb, 0.f);
            pl[i] += (v * sc + sh) * ow;
        }
    }
    #pragma unroll
    for (int m = 1; m < 16; m <<= 1)
        #pragma unroll
        for (int i = 0; i < 4; i++) pl[i] += __shfl_xor(pl[i], m);
    if (lane15 == 0) {
        #pragma unroll
        for (int i = 0; i < 4; i++) red[(mtile * 16 + quad * 4 + i) * 2 + nhalf] = pl[i];
    }
    __syncthreads();
    if (t < 32) {
        float s = red[t * 2] + red[t * 2 + 1] + outb[0];
        out[blockIdx.x * 32 + t] = 1.f / (1.f + expf(-s));
    }
}

// ---------------------------------------------------------------------------
extern "C" void kernel_launch(void* const* d_in, const int* in_sizes, int n_in,
                              void* d_out, int out_size, void* d_ws, size_t ws_size,
                              hipStream_t stream) {
    const int*   sp       = (const int*)d_in[0];
    const float* dn       = (const float*)d_in[1];
    const float* gen_tab  = (const float*)d_in[2];
    const float* gen_W    = (const float*)d_in[3];
    const float* gen_b    = (const float*)d_in[4];
    const float* cls_tab  = (const float*)d_in[5];
    const float* cls_W    = (const float*)d_in[6];
    const float* cls_b    = (const float*)d_in[7];
    const float* conv_k0  = (const float*)d_in[8];
    const float* conv_b0  = (const float*)d_in[9];
    const float* fc_W0    = (const float*)d_in[10];
    const float* fc_b0    = (const float*)d_in[11];
    const float* conv_k1  = (const float*)d_in[12];
    const float* conv_b1  = (const float*)d_in[13];
    const float* fc_W1    = (const float*)d_in[14];
    const float* fc_b1    = (const float*)d_in[15];
    const float* mlp_W1   = (const float*)d_in[16];
    const float* mlp_b1   = (const float*)d_in[17];
    const float* bn_gamma = (const float*)d_in[18];
    const float* bn_beta  = (const float*)d_in[19];
    const float* bn_mean  = (const float*)d_in[20];
    const float* bn_var   = (const float*)d_in[21];
    const float* out_W    = (const float*)d_in[22];
    const float* out_b    = (const float*)d_in[23];
    float* out = (float*)d_out;

    // workspace layout (bytes):
    // pooled0  bf16 B*3328*2 = 54,525,952 @ 0        (later aliased by h bf16 B*1600*2 = 26,214,400)
    // pooled1  bf16 B*1536*2 = 25,165,824 @ 54,525,952
    // embs_cls bf16 B*864*2  = 14,155,776 @ 79,691,776
    // p0a/p0b  f32  B*96*4   =  3,145,728 @ 93,847,552 / 96,993,280
    // p1a/p1b  f32  B*96*4   =  3,145,728 @ 100,139,008 / 103,284,736
    // Wt0 bf16 96*3328*2     =    638,976 @ 106,430,464
    // Wt1 bf16 96*1536*2     =    294,912 @ 107,069,440
    // Wt2 bf16 128*1600*2    =    409,600 @ 107,364,352   -> end 107,773,952
    char* ws = (char*)d_ws;
    bf16_t* pooled0  = (bf16_t*)(ws + 0);
    bf16_t* pooled1  = (bf16_t*)(ws + 54525952ULL);
    bf16_t* embs_cls = (bf16_t*)(ws + 79691776ULL);
    float*  p0a      = (float*)(ws + 93847552ULL);
    float*  p0b      = (float*)(ws + 96993280ULL);
    float*  p1a      = (float*)(ws + 100139008ULL);
    float*  p1b      = (float*)(ws + 103284736ULL);
    bf16_t* Wt0      = (bf16_t*)(ws + 106430464ULL);
    bf16_t* Wt1      = (bf16_t*)(ws + 107069440ULL);
    bf16_t* Wt2      = (bf16_t*)(ws + 107364352ULL);
    bf16_t* h        = (bf16_t*)(ws + 0);   // aliases pooled0 (consumed before build_h)

    k_wprep<<<(96 * 3328 + 255) / 256, 256, 0, stream>>>(fc_W0, fc_W1, mlp_W1, Wt0, Wt1, Wt2);
    k_embed_conv0<<<BATCH, 256, 0, stream>>>(sp, dn, gen_tab, gen_W, gen_b,
                                             cls_tab, cls_W, cls_b,
                                             conv_k0, conv_b0, pooled0, embs_cls);
    k_fc_mfma<3328, 52><<<dim3(BATCH / 64, 2), 256, 0, stream>>>(pooled0, Wt0, p0a, p0b);
    k_conv1<<<BATCH, 256, 0, stream>>>(pooled0, conv_k1, conv_b1, pooled1);
    k_fc_mfma<1536, 24><<<dim3(BATCH / 64, 2), 256, 0, stream>>>(pooled1, Wt1, p1a, p1b);
    k_build_h<<<BATCH, 256, 0, stream>>>(embs_cls, p0a, p0b, fc_b0, p1a, p1b, fc_b1, h);
    k_mlp_mfma<<<BATCH / 32, 256, 0, stream>>>(h, Wt2, mlp_b1, bn_gamma, bn_beta,
                                               bn_mean, bn_var, out_W, out_b, out);
}